// Round 13
// baseline (277.890 us; speedup 1.0000x reference)
//
#include <hip/hip_runtime.h>

typedef __bf16 bf16_t;
typedef __bf16 bf16x8 __attribute__((ext_vector_type(8)));
typedef __bf16 bf16x4v __attribute__((ext_vector_type(4)));
typedef __bf16 bf16x2v __attribute__((ext_vector_type(2)));
typedef float f32x4 __attribute__((ext_vector_type(4)));
typedef unsigned long long u64;

#define LN_EPS 1e-5f

// njuffa's 1-ulp erff (fast path for |a|<=0.921875 is 6 fma)
__device__ __forceinline__ float erf_fast(float a) {
  const float t = fabsf(a);
  const float s = a * a;
  float r;
  if (t > 0.921875f) {
    float u;
    r = fmaf(-1.72853470e-5f, t, 3.83197126e-4f);
    u = fmaf(-3.88396438e-3f, t, 2.42546219e-2f);
    r = fmaf(r, s, u);
    r = fmaf(r, t, 1.06777877e-1f);
    r = fmaf(r, t, -6.37245935e-1f);
    r = fmaf(r, t, -1.28717512e-1f);
    r = fmaf(r, t, t);
    r = 1.0f - __expf(-r);
    r = copysignf(r, a);
  } else {
    r = -5.96761703e-4f;
    r = fmaf(r, s, 4.99119423e-3f);
    r = fmaf(r, s, -2.67681349e-2f);
    r = fmaf(r, s, 1.12819925e-1f);
    r = fmaf(r, s, -3.76125336e-1f);
    r = fmaf(r, s, 1.28379166e-1f);
    r = fmaf(r, a, a);
  }
  return r;
}

__device__ __forceinline__ float gelu_f(float x) {
  const float h = 0.5f * x;
  return fmaf(h, erf_fast(x * 0.70710678118654752f), h);
}

__device__ __forceinline__ void async16(const bf16_t* g, bf16_t* l) {
  __builtin_amdgcn_global_load_lds(
      (const __attribute__((address_space(1))) void*)g,
      (__attribute__((address_space(3))) void*)l, 16, 0, 0);
}

// ---------------------------------------------------------------------------
// prep: X,S -> bf16 ; weights -> transposed bf16 ; zero bitmap+gatelin
// Bulk sections do 4 independent float4 per thread (ILP).
// ---------------------------------------------------------------------------
__global__ __launch_bounds__(256)
void prep_kernel(const float* __restrict__ X, const float* __restrict__ S,
                 const float* __restrict__ Wg, const float* __restrict__ Wk,
                 const float* __restrict__ Wm1, const float* __restrict__ Wgt1,
                 const float* __restrict__ Wm2, const float* __restrict__ Wqkv,
                 const float* __restrict__ Wo, const float* __restrict__ Wu1,
                 const float* __restrict__ Wu2,
                 bf16_t* __restrict__ Xb, bf16_t* __restrict__ Sb,
                 bf16_t* __restrict__ W1t, bf16_t* __restrict__ W2t,
                 bf16_t* __restrict__ Wqkvt, bf16_t* __restrict__ Wot,
                 bf16_t* __restrict__ Wu1t, bf16_t* __restrict__ Wu2t,
                 float4* __restrict__ zbase)
{
  const int bid = blockIdx.x;
  const int t = threadIdx.x;
  if (bid < 2048) {                       // X: 4 float4 per thread
    const int base = bid * 1024 + t;
#pragma unroll
    for (int j = 0; j < 4; ++j) {
      const int i = base + j * 256;
      const float4 v = ((const float4*)X)[i];
      bf16x4v o; o[0]=(bf16_t)v.x; o[1]=(bf16_t)v.y; o[2]=(bf16_t)v.z; o[3]=(bf16_t)v.w;
      ((bf16x4v*)Xb)[i] = o;
    }
  } else if (bid < 2304) {                // S: 4 float4 per thread
    const int base = (bid - 2048) * 1024 + t;
#pragma unroll
    for (int j = 0; j < 4; ++j) {
      const int i = base + j * 256;
      const float4 v = ((const float4*)S)[i];
      bf16x4v o; o[0]=(bf16_t)v.x; o[1]=(bf16_t)v.y; o[2]=(bf16_t)v.z; o[3]=(bf16_t)v.w;
      ((bf16x4v*)Sb)[i] = o;
    }
  } else if (bid < 3200) {                // W1t: 896 rows x 256
    const int n = bid - 2304;
    const int k = t;
    float v;
    if (n < 512)      v = Wm1[k * 512 + n];
    else if (n < 768) v = Wgt1[k * 256 + (n - 512)];
    else if (n < 832) v = Wg[k * 64 + (n - 768)];
    else if (n < 840) v = Wk[k * 8 + (n - 832)];
    else              v = 0.f;
    W1t[n * 256 + k] = (bf16_t)v;
  } else if (bid < 3456) {                // W2t: 256 rows x 512
    const int n = bid - 3200;
    for (int k = t; k < 512; k += 256) W2t[n * 512 + k] = (bf16_t)Wm2[k * 256 + n];
  } else if (bid < 4224) {                // Wqkvt: 768 x 256
    const int n = bid - 3456;
    Wqkvt[n * 256 + t] = (bf16_t)Wqkv[t * 768 + n];
  } else if (bid < 4480) {                // Wot: 256 x 256
    const int n = bid - 4224;
    Wot[n * 256 + t] = (bf16_t)Wo[t * 256 + n];
  } else if (bid < 4992) {                // Wu1t: 512 x 512
    const int n = bid - 4480;
    for (int k = t; k < 512; k += 256) Wu1t[n * 512 + k] = (bf16_t)Wu1[k * 512 + n];
  } else if (bid < 5248) {                // Wu2t: 256 x 512
    const int n = bid - 4992;
    for (int k = t; k < 512; k += 256) Wu2t[n * 512 + k] = (bf16_t)Wu2[k * 256 + n];
  } else {                                // zero bitmap (2MB) + gatelin (128KB)
    const int base = (bid - 5248) * 1024 + t;
#pragma unroll
    for (int j = 0; j < 4; ++j)
      zbase[base + j * 256] = make_float4(0.f, 0.f, 0.f, 0.f);
  }
}

// ---------------------------------------------------------------------------
// g1qkv: merged dispatch.
//   blocks [0,1792): g1 = Xb @ W1t^T with fused routing epilogue
//     (128x128 tile, 4 waves, wave 64x64, acc[4][4]; (256,2) proven optimum)
//   blocks [1792,2176): qkv = Sb @ Wqkvt^T + bqkv (depends only on prep).
// XOR-swizzled LDS in g1 path (slot s of row r holds chunk s^(r&3)).
// ---------------------------------------------------------------------------
__global__ __launch_bounds__(256, 2)
void g1qkv_kernel(const bf16_t* __restrict__ A,
                  const bf16_t* __restrict__ Bt,
                  const float* __restrict__ bias, const float* __restrict__ bias2,
                  bf16_t* __restrict__ h1,
                  const float* __restrict__ wgt2, float* __restrict__ gatelin,
                  u64* __restrict__ bitmap,
                  const bf16_t* __restrict__ Sb, const bf16_t* __restrict__ Wqkvt,
                  const float* __restrict__ bqkv, bf16_t* __restrict__ qkvb,
                  bf16_t* __restrict__ Vt)
{
  const int bid = blockIdx.x;
  const int t = threadIdx.x;
  const int w = t >> 6;
  const int lane = t & 63;
  const int wr = w >> 1, wc = w & 1;
  const int quad = lane >> 4, l15 = lane & 15;

  __shared__ bf16_t lA[128 * 32];
  __shared__ bf16_t lB[128 * 32];
  __shared__ float sWg[256];
  __shared__ int sKi[128];

  if (bid >= 1792) {
    // ---------------- qkv path (64-row tile) -------
    const int id = bid - 1792;
    const int m0 = (id & 63) * 64;
    const int n0 = (id >> 6) * 128;

    f32x4 acc[2][4];
#pragma unroll
    for (int mt = 0; mt < 2; ++mt)
#pragma unroll
      for (int nt = 0; nt < 4; ++nt)
        acc[mt][nt] = (f32x4){0.f, 0.f, 0.f, 0.f};

    for (int k0 = 0; k0 < 256; k0 += 32) {
      async16(Sb + (size_t)(m0 + (t >> 2)) * 256 + k0 + (t & 3) * 8,
              lA + (size_t)(t & 192) * 8);
#pragma unroll
      for (int i = 0; i < 2; ++i) {
        const int c = i * 256 + t;
        async16(Wqkvt + (size_t)(n0 + (c >> 2)) * 256 + k0 + (c & 3) * 8,
                lB + (size_t)(i * 256 + (t & 192)) * 8);
      }
      __syncthreads();
      bf16x8 af[2], bfr[4];
      const int ko = quad * 8;
#pragma unroll
      for (int mt = 0; mt < 2; ++mt)
        af[mt] = *(const bf16x8*)&lA[(wr * 32 + mt * 16 + l15) * 32 + ko];
#pragma unroll
      for (int nt = 0; nt < 4; ++nt)
        bfr[nt] = *(const bf16x8*)&lB[(wc * 64 + nt * 16 + l15) * 32 + ko];
#pragma unroll
      for (int mt = 0; mt < 2; ++mt)
#pragma unroll
        for (int nt = 0; nt < 4; ++nt)
          acc[mt][nt] = __builtin_amdgcn_mfma_f32_16x16x32_bf16(bfr[nt], af[mt], acc[mt][nt], 0, 0, 0);
      __syncthreads();
    }

    if (n0 < 512) {
      // Q/K: row-major qkvb (ldc=768)
#pragma unroll
      for (int mt = 0; mt < 2; ++mt) {
        const int row = m0 + wr * 32 + mt * 16 + l15;
#pragma unroll
        for (int nt = 0; nt < 4; ++nt) {
          const int colb = n0 + wc * 64 + nt * 16 + quad * 4;
          const float4 bb = *(const float4*)&bqkv[colb];
          bf16x4v o; o[0]=(bf16_t)(acc[mt][nt][0]+bb.x); o[1]=(bf16_t)(acc[mt][nt][1]+bb.y);
          o[2]=(bf16_t)(acc[mt][nt][2]+bb.z); o[3]=(bf16_t)(acc[mt][nt][3]+bb.w);
          *(bf16x4v*)&qkvb[(size_t)row * 768 + colb] = o;
        }
      }
    } else {
      // V: transposed -> Vt[((b*8+h)*32 + dh)*512 + key]
#pragma unroll
      for (int mt = 0; mt < 2; ++mt) {
        const int row = m0 + wr * 32 + mt * 16 + l15;
        const int b = row >> 9, key = row & 511;
#pragma unroll
        for (int nt = 0; nt < 4; ++nt) {
          const int colb = n0 + wc * 64 + nt * 16 + quad * 4;
          const int c = colb - 512;
          const int h2 = c >> 5, dh = c & 31;
          const float4 bb = *(const float4*)&bqkv[colb];
          bf16_t* vb = Vt + ((size_t)(b * 8 + h2) * 32 + dh) * 512 + key;
          vb[0]   = (bf16_t)(acc[mt][nt][0] + bb.x);
          vb[512] = (bf16_t)(acc[mt][nt][1] + bb.y);
          vb[1024]= (bf16_t)(acc[mt][nt][2] + bb.z);
          vb[1536]= (bf16_t)(acc[mt][nt][3] + bb.w);
        }
      }
    }
    return;
  }

  // ---------------- g1 path (proven 44.9us kernel) -------
  const int m0 = (bid & 255) * 128;
  const int by = bid >> 8;
  const int n0 = by * 128;

  if (by >= 4 && by < 6) sWg[t] = wgt2[t];

  f32x4 acc[4][4];
#pragma unroll
  for (int mt = 0; mt < 4; ++mt)
#pragma unroll
    for (int nt = 0; nt < 4; ++nt)
      acc[mt][nt] = (f32x4){0.f, 0.f, 0.f, 0.f};

  const int srow = t >> 2;                             // row within 64-row half
  const int schunk = ((t & 3) ^ (srow & 3)) * 8;       // swizzled source chunk
  const int ko = ((quad ^ (l15 & 3)) << 3);            // swizzled read offset

  for (int k0 = 0; k0 < 256; k0 += 32) {
#pragma unroll
    for (int i = 0; i < 2; ++i) {
      const int row = i * 64 + srow;
      async16(A + (size_t)(m0 + row) * 256 + k0 + schunk,
              lA + (size_t)(i * 256 + (t & 192)) * 8);
      async16(Bt + (size_t)(n0 + row) * 256 + k0 + schunk,
              lB + (size_t)(i * 256 + (t & 192)) * 8);
    }
    __syncthreads();
    bf16x8 af[4], bfr[4];
#pragma unroll
    for (int mt = 0; mt < 4; ++mt)
      af[mt] = *(const bf16x8*)&lA[(wr * 64 + mt * 16 + l15) * 32 + ko];
#pragma unroll
    for (int nt = 0; nt < 4; ++nt)
      bfr[nt] = *(const bf16x8*)&lB[(wc * 64 + nt * 16 + l15) * 32 + ko];
#pragma unroll
    for (int mt = 0; mt < 4; ++mt)
#pragma unroll
      for (int nt = 0; nt < 4; ++nt)
        acc[mt][nt] = __builtin_amdgcn_mfma_f32_16x16x32_bf16(bfr[nt], af[mt], acc[mt][nt], 0, 0, 0);
    __syncthreads();
  }

  if (by < 4) {
    // msg: gelu(v + bm1) -> h1 bf16, ldc = 512
#pragma unroll
    for (int mt = 0; mt < 4; ++mt) {
      const int row = m0 + wr * 64 + mt * 16 + l15;
#pragma unroll
      for (int nt = 0; nt < 4; ++nt) {
        const int colb = n0 + wc * 64 + nt * 16 + quad * 4;
        const float4 bb = *(const float4*)&bias[colb];
        bf16x4v o;
        o[0] = (bf16_t)gelu_f(acc[mt][nt][0] + bb.x);
        o[1] = (bf16_t)gelu_f(acc[mt][nt][1] + bb.y);
        o[2] = (bf16_t)gelu_f(acc[mt][nt][2] + bb.z);
        o[3] = (bf16_t)gelu_f(acc[mt][nt][3] + bb.w);
        *(bf16x4v*)&h1[(size_t)row * 512 + colb] = o;
      }
    }
  } else if (by < 6) {
    // gate strips: partial dot of gelu(g1) with Wgt2 -> atomicAdd gatelin
#pragma unroll
    for (int mt = 0; mt < 4; ++mt) {
      const int row = m0 + wr * 64 + mt * 16 + l15;
      float part = 0.f;
#pragma unroll
      for (int nt = 0; nt < 4; ++nt) {
        const int colb = n0 + wc * 64 + nt * 16 + quad * 4;
        const int c = colb - 512;
        const float4 bb = *(const float4*)&bias2[c];
        part = fmaf(gelu_f(acc[mt][nt][0] + bb.x), sWg[c + 0], part);
        part = fmaf(gelu_f(acc[mt][nt][1] + bb.y), sWg[c + 1], part);
        part = fmaf(gelu_f(acc[mt][nt][2] + bb.z), sWg[c + 2], part);
        part = fmaf(gelu_f(acc[mt][nt][3] + bb.w), sWg[c + 3], part);
      }
      part += __shfl_xor(part, 16, 64);
      part += __shfl_xor(part, 32, 64);
      if (lane < 16) atomicAdd(&gatelin[row], part);
    }
  } else {
    // logit strip: argmax(g)*8 + argmax(k) -> bitmap
    int bi[4];
#pragma unroll
    for (int mt = 0; mt < 4; ++mt) {
      if (wc == 0) {
        float mv = -1e30f; int mi = 0;
#pragma unroll
        for (int nt = 0; nt < 4; ++nt)
#pragma unroll
          for (int j = 0; j < 4; ++j) {
            const int gc = nt * 16 + quad * 4 + j;
            const float v = acc[mt][nt][j];
            if (v > mv || (v == mv && gc < mi)) { mv = v; mi = gc; }
          }
#pragma unroll
        for (int off = 16; off <= 32; off <<= 1) {
          const float ov = __shfl_xor(mv, off, 64);
          const int oi = __shfl_xor(mi, off, 64);
          if (ov > mv || (ov == mv && oi < mi)) { mv = ov; mi = oi; }
        }
        bi[mt] = mi;
      } else {
        float mv = -1e30f; int mi = 0;
        if (quad < 2) {
#pragma unroll
          for (int j = 0; j < 4; ++j) {
            const int kc = quad * 4 + j;
            const float v = acc[mt][0][j];
            if (v > mv || (v == mv && kc < mi)) { mv = v; mi = kc; }
          }
        }
#pragma unroll
        for (int off = 16; off <= 32; off <<= 1) {
          const float ov = __shfl_xor(mv, off, 64);
          const int oi = __shfl_xor(mi, off, 64);
          if (ov > mv || (ov == mv && oi < mi)) { mv = ov; mi = oi; }
        }
        if (lane < 16) sKi[wr * 64 + mt * 16 + l15] = mi;
      }
    }
    __syncthreads();
    if (wc == 0 && lane < 16) {
#pragma unroll
      for (int mt = 0; mt < 4; ++mt) {
        const int rl = wr * 64 + mt * 16 + l15;
        const int row = m0 + rl;
        const int idx = bi[mt] * 8 + sKi[rl];
        const int b = row >> 12, tok = row & 4095;
        atomicOr(&bitmap[(size_t)(b * 512 + idx) * 64 + (tok >> 6)],
                 1ull << (tok & 63));
      }
    }
  }
}

// ---------------------------------------------------------------------------
// gather: block per (b,slot); WAVE-PARALLEL bitmap walk.
//   wave w owns bitmap words [16w, 16w+16) -> 4 independent token chains
//   (4x shorter serial path, 4x memory parallelism vs old whole-block walk).
//   lane owns 8 columns (bf16x8 coalesced row read); 1-deep manual prefetch
//   (addresses don't depend on loaded data). Cross-wave reduce via LDS.
// ---------------------------------------------------------------------------
__global__ __launch_bounds__(256)
void gather_kernel(const bf16_t* __restrict__ h1, const float* __restrict__ gatelin,
                   const float* __restrict__ bgt2, const u64* __restrict__ bitmap,
                   bf16_t* __restrict__ H, float* __restrict__ sumg)
{
  const int bs = blockIdx.x;
  const int b = bs >> 9;
  const int t = threadIdx.x;
  const int w = t >> 6, lane = t & 63;
  __shared__ u64 sw[64];
  __shared__ float pa[4][512];
  __shared__ float psg[4];
  if (t < 64) sw[t] = bitmap[(size_t)bs * 64 + t];
  __syncthreads();
  const float bg = bgt2[0];

  float a[8];
#pragma unroll
  for (int j = 0; j < 8; ++j) a[j] = 0.f;
  float sg = 0.f;

  int wd = w * 16;
  const int wend = wd + 16;
  u64 word = sw[wd];
  auto pop = [&]() -> int {
    while (word == 0) {
      if (++wd >= wend) return -1;
      word = sw[wd];
    }
    const int bit = __builtin_ctzll(word);
    word &= word - 1;
    return (b << 12) + (wd << 6) + bit;
  };

  int l0 = pop();
  float gl0 = 0.f;
  bf16x8 hv0 = {};
  if (l0 >= 0) {
    gl0 = gatelin[l0];
    hv0 = *(const bf16x8*)&h1[(size_t)l0 * 512 + lane * 8];
  }
  while (l0 >= 0) {
    const int l1 = pop();
    float gl1 = 0.f;
    bf16x8 hv1 = {};
    if (l1 >= 0) {                       // prefetch next token while consuming cur
      gl1 = gatelin[l1];
      hv1 = *(const bf16x8*)&h1[(size_t)l1 * 512 + lane * 8];
    }
    const float g = 1.0f / (1.0f + __expf(-(gl0 + bg)));
#pragma unroll
    for (int j = 0; j < 8; ++j) a[j] = fmaf(g, (float)hv0[j], a[j]);
    sg += g;
    l0 = l1; gl0 = gl1; hv0 = hv1;
  }

#pragma unroll
  for (int j = 0; j < 8; ++j) pa[w][lane * 8 + j] = a[j];
  if (lane == 0) psg[w] = sg;
  __syncthreads();

  const int c = t * 2;
  const float r0 = pa[0][c] + pa[1][c] + pa[2][c] + pa[3][c];
  const float r1 = pa[0][c + 1] + pa[1][c + 1] + pa[2][c + 1] + pa[3][c + 1];
  bf16x2v o; o[0] = (bf16_t)r0; o[1] = (bf16_t)r1;
  *(bf16x2v*)&H[(size_t)bs * 512 + c] = o;
  if (t == 0) sumg[bs] = psg[0] + psg[1] + psg[2] + psg[3];
}

// ---------------------------------------------------------------------------
// g2attn: merged dispatch.
//   blocks [0,128): G2' (incoming = H@Wm2 + sumg*bm2, f32, 64-row tiles)
//   blocks [128,1152): fused slot attention (b, h, 32-query chunk), 4 waves.
// ---------------------------------------------------------------------------
__global__ __launch_bounds__(256)
void g2attn_kernel(const bf16_t* __restrict__ qkv, const bf16_t* __restrict__ Vt,
                   bf16_t* __restrict__ obuf,
                   const bf16_t* __restrict__ H, const bf16_t* __restrict__ W2t,
                   const float* __restrict__ bm2, const float* __restrict__ sumg,
                   float* __restrict__ incom)
{
  const int bid = blockIdx.x;
  const int t = threadIdx.x;
  const int w = t >> 6, lane = t & 63;
  const int quad = lane >> 4, l15 = lane & 15;

  __shared__ bf16_t sP[32 * 520];
  __shared__ float sL[32];

  if (bid < 128) {
    // ---------------- G2' path (64-row tile) ------
    const int wr = w >> 1, wc = w & 1;
    const int m0 = (bid & 63) * 64;
    const int n0 = (bid >> 6) * 128;
    bf16_t* lA = sP;                 // 64*32 elems
    bf16_t* lB = sP + 64 * 32;       // 128*32 elems

    f32x4 acc[2][4];
#pragma unroll
    for (int mt = 0; mt < 2; ++mt)
#pragma unroll
      for (int nt = 0; nt < 4; ++nt)
        acc[mt][nt] = (f32x4){0.f, 0.f, 0.f, 0.f};

    for (int k0 = 0; k0 < 512; k0 += 32) {
      async16(H + (size_t)(m0 + (t >> 2)) * 512 + k0 + (t & 3) * 8,
              lA + (size_t)(t & 192) * 8);
#pragma unroll
      for (int i = 0; i < 2; ++i) {
        const int c = i * 256 + t;
        async16(W2t + (size_t)(n0 + (c >> 2)) * 512 + k0 + (c & 3) * 8,
                lB + (size_t)(i * 256 + (t & 192)) * 8);
      }
      __syncthreads();
      bf16x8 af[2], bfr[4];
      const int ko = quad * 8;
#pragma unroll
      for (int mt = 0; mt < 2; ++mt)
        af[mt] = *(const bf16x8*)&lA[(wr * 32 + mt * 16 + l15) * 32 + ko];
#pragma unroll
      for (int nt = 0; nt < 4; ++nt)
        bfr[nt] = *(const bf16x8*)&lB[(wc * 64 + nt * 16 + l15) * 32 + ko];
#pragma unroll
      for (int mt = 0; mt < 2; ++mt)
#pragma unroll
        for (int nt = 0; nt < 4; ++nt)
          acc[mt][nt] = __builtin_amdgcn_mfma_f32_16x16x32_bf16(bfr[nt], af[mt], acc[mt][nt], 0, 0, 0);
      __syncthreads();
    }

#pragma unroll
    for (int mt = 0; mt < 2; ++mt) {
      const int row = m0 + wr * 32 + mt * 16 + l15;
      const float gt = sumg[row];
#pragma unroll
      for (int nt = 0; nt < 4; ++nt) {
        const int colb = n0 + wc * 64 + nt * 16 + quad * 4;
        const float4 bb = *(const float4*)&bm2[colb];
        *(float4*)&incom[(size_t)row * 256 + colb] =
            make_float4(fmaf(gt, bb.x, acc[mt][nt][0]), fmaf(gt, bb.y, acc[mt][nt][1]),
                        fmaf(gt, bb.z, acc[mt][nt][2]), fmaf(gt, bb.w, acc[mt][nt][3]));
      }
    }
    return;
  }

  // ---------------- attention path ------
  const int abid = bid - 128;
  const int qc = abid & 15;
  const int h = (abid >> 4) & 7;
  const int b = abid >> 7;

  bf16x8 qf[2];
#pragma unroll
  for (int mt = 0; mt < 2; ++mt) {
    const int row = b * 512 + qc * 32 + mt * 16 + l15;
    qf[mt] = *(const bf16x8*)&qkv[(size_t)row * 768 + h * 32 + quad * 8];
  }
  const float scale = 0.17677669529663687f;  // 1/sqrt(32)
  for (int kt = w; kt < 32; kt += 4) {
    const int key = b * 512 + kt * 16 + l15;
    const bf16x8 kf = *(const bf16x8*)&qkv[(size_t)key * 768 + 256 + h * 32 + quad * 8];
#pragma unroll
    for (int mt = 0; mt < 2; ++mt) {
      f32x4 c = (f32x4){0.f, 0.f, 0.f, 0.f};
      c = __builtin_amdgcn_mfma_f32_16x16x32_bf16(qf[mt], kf, c, 0, 0, 0);
#pragma unroll
      for (int r = 0; r < 4; ++r)
        sP[(mt * 16 + quad * 4 + r) * 520 + kt * 16 + l15] = (bf16_t)(c[r] * scale);
    }
  }
  __syncthreads();

#pragma unroll
  for (int ri = 0; ri < 8; ++ri) {
    const int row = w * 8 + ri;
    const bf16x8 sv = *(const bf16x8*)&sP[row * 520 + lane * 8];
    float sval[8];
    float mx = -1e30f;
#pragma unroll
    for (int j = 0; j < 8; ++j) { sval[j] = (float)sv[j]; mx = fmaxf(mx, sval[j]); }
#pragma unroll
    for (int off = 32; off; off >>= 1) mx = fmaxf(mx, __shfl_xor(mx, off, 64));
    float sum = 0.f;
    bf16x8 pv;
#pragma unroll
    for (int j = 0; j < 8; ++j) { const float e = __expf(sval[j] - mx); sum += e; pv[j] = (bf16_t)e; }
#pragma unroll
    for (int off = 32; off; off >>= 1) sum += __shfl_xor(sum, off, 64);
    *(bf16x8*)&sP[row * 520 + lane * 8] = pv;
    if (lane == 0) sL[row] = sum;
  }
  __syncthreads();

  // PV: wave (wq, wd) computes O[qc*32 + wq*16 + q][wd*16 + dh-range]
  const int wq = w >> 1, wd = w & 1;
  const bf16_t* vbase = Vt + ((size_t)(b * 8 + h) * 32 + wd * 16 + l15) * 512;
  const bf16_t* pbase = &sP[(wq * 16 + l15) * 520];
  f32x4 oacc = (f32x4){0.f, 0.f, 0.f, 0.f};
#pragma unroll
  for (int kt = 0; kt < 16; ++kt) {
    const bf16x8 af = *(const bf16x8*)&pbase[kt * 32 + quad * 8];
    const bf16x8 vf = *(const bf16x8*)&vbase[kt * 32 + quad * 8];
    oacc = __builtin_amdgcn_mfma_f32_16x16x32_bf16(vf, af, oacc, 0, 0, 0);
  }
  const int rowq = wq * 16 + l15;
  const float inv = 1.0f / sL[rowq];
  bf16x4v o;
#pragma unroll
  for (int r = 0; r < 4; ++r) o[r] = (bf16_t)(oacc[r] * inv);
  *(bf16x4v*)&obuf[(size_t)(b * 512 + qc * 32 + rowq) * 256 + h * 32 + wd * 16 + quad * 4] = o;
}

// ---------------------------------------------------------------------------
// tail: fused wo_ln1 + wu1 + wu2_ln2 (row-local chain, LDS intermediates).
// Block = 16 rows, 256 threads, 4 waves.
// ---------------------------------------------------------------------------
__global__ __launch_bounds__(256)
void tail_kernel(const bf16_t* __restrict__ obuf, const bf16_t* __restrict__ Wot,
                 const float* __restrict__ bo, const float* __restrict__ S,
                 const float* __restrict__ incom,
                 const float* __restrict__ g1n, const float* __restrict__ b1n,
                 const bf16_t* __restrict__ Wu1t, const float* __restrict__ bu1,
                 const bf16_t* __restrict__ Wu2t, const float* __restrict__ bu2,
                 const float* __restrict__ g2n, const float* __restrict__ b2n,
                 float* __restrict__ out)
{
  const int m0 = blockIdx.x * 16;
  const int t = threadIdx.x;
  const int w = t >> 6, lane = t & 63;
  const int quad = lane >> 4, l15 = lane & 15;

  __shared__ bf16_t lB[512 * 32];     // 32KB staging (phases use a prefix)
  __shared__ bf16_t lA[16 * 32];      // obuf staging (phase 1)
  __shared__ bf16_t A4s[16 * 520];    // [S1|incom] bf16, padded stride
  __shared__ bf16_t Us[16 * 520];     // hidden bf16, padded stride
  __shared__ float sSum[4][16];
  __shared__ float sSq[4][16];

  const int schunk = ((t & 3) ^ ((t >> 2) & 3)) * 8;   // swizzled B source chunk
  const int ko_b = ((quad ^ (l15 & 3)) << 3);          // swizzled B read offset
  const int ko_a = quad * 8;                           // plain A read offset
  const int row = m0 + l15;

  // ---------------- phase 1: S1 = LN(S + obuf@Wot + bo) ----------------
  {
    f32x4 acc[4];
#pragma unroll
    for (int nt = 0; nt < 4; ++nt) acc[nt] = (f32x4){0.f, 0.f, 0.f, 0.f};

    for (int k0 = 0; k0 < 256; k0 += 32) {
      if (t < 64)
        async16(obuf + (size_t)(m0 + (t >> 2)) * 256 + k0 + (t & 3) * 8, lA);
#pragma unroll
      for (int i = 0; i < 4; ++i) {
        const int c = i * 256 + t;
        async16(Wot + (size_t)(c >> 2) * 256 + k0 + schunk,
                lB + (size_t)(i * 256 + (t & 192)) * 8);
      }
      __syncthreads();
      const bf16x8 af = *(const bf16x8*)&lA[l15 * 32 + ko_a];
#pragma unroll
      for (int nt = 0; nt < 4; ++nt) {
        const bf16x8 bfr = *(const bf16x8*)&lB[(w * 64 + nt * 16 + l15) * 32 + ko_b];
        acc[nt] = __builtin_amdgcn_mfma_f32_16x16x32_bf16(bfr, af, acc[nt], 0, 0, 0);
      }
      __syncthreads();
    }

    float sum = 0.f, sq = 0.f;
#pragma unroll
    for (int nt = 0; nt < 4; ++nt) {
      const int colb = w * 64 + nt * 16 + quad * 4;
      const float4 bv = *(const float4*)&bo[colb];
      const float4 sv = *(const float4*)&S[(size_t)row * 256 + colb];
      float x0 = acc[nt][0] + bv.x + sv.x, x1 = acc[nt][1] + bv.y + sv.y;
      float x2 = acc[nt][2] + bv.z + sv.z, x3 = acc[nt][3] + bv.w + sv.w;
      acc[nt][0] = x0; acc[nt][1] = x1; acc[nt][2] = x2; acc[nt][3] = x3;
      sum += x0 + x1 + x2 + x3;
      sq += x0*x0 + x1*x1 + x2*x2 + x3*x3;
    }
    sum += __shfl_xor(sum, 16, 64); sum += __shfl_xor(sum, 32, 64);
    sq  += __shfl_xor(sq, 16, 64);  sq  += __shfl_xor(sq, 32, 64);
    if (lane < 16) { sSum[w][l15] = sum; sSq[w][l15] = sq; }
    __syncthreads();
    const float tot = sSum[0][l15] + sSum[1][l15] + sSum[2][l15] + sSum[3][l15];
    const float tq  = sSq[0][l15] + sSq[1][l15] + sSq[2][l15] + sSq[3][l15];
    const float mean = tot * 0.00390625f;
    const float var = tq * 0.00390625f - mean * mean;
    const float rstd = rsqrtf(var + LN_EPS);
#pragma unroll
    for (int nt = 0; nt < 4; ++nt) {
      const int colb = w * 64 + nt * 16 + quad * 4;
      const float4 gg = *(const float4*)&g1n[colb];
      const float4 bv = *(const float4*)&b1n[colb];
      bf16x4v yb;
      yb[0] = (bf16_t)((acc[nt][0]-mean)*rstd*gg.x + bv.x);
      yb[1] = (bf16_t)((acc[nt][1]-mean)*rstd*gg.y + bv.y);
      yb[2] = (bf16_t)((acc[nt][2]-mean)*rstd*gg.z + bv.z);
      yb[3] = (bf16_t)((acc[nt][3]-mean)*rstd*gg.w + bv.w);
      *(bf16x4v*)&A4s[l15 * 520 + colb] = yb;
      const float4 ic = *(const float4*)&incom[(size_t)row * 256 + colb];
      bf16x4v ib; ib[0]=(bf16_t)ic.x; ib[1]=(bf16_t)ic.y; ib[2]=(bf16_t)ic.z; ib[3]=(bf16_t)ic.w;
      *(bf16x4v*)&A4s[l15 * 520 + 256 + colb] = ib;
    }
  }
  __syncthreads();

  // ---------------- phase 2: h = gelu(A4s @ Wu1t + bu1) -> Us ----------------
  {
    f32x4 acc2[8];
#pragma unroll
    for (int nt = 0; nt < 8; ++nt) acc2[nt] = (f32x4){0.f, 0.f, 0.f, 0.f};

    for (int k0 = 0; k0 < 512; k0 += 32) {
#pragma unroll
      for (int i = 0; i < 8; ++i) {
        const int c = i * 256 + t;
        async16(Wu1t + (size_t)(c >> 2) * 512 + k0 + schunk,
                lB + (size_t)(i * 256 + (t & 192)) * 8);
      }
      __syncthreads();
      const bf16x8 af = *(const bf16x8*)&A4s[l15 * 520 + k0 + ko_a];
#pragma unroll
      for (int nt = 0; nt < 8; ++nt) {
        const bf16x8 bfr = *(const bf16x8*)&lB[(w * 128 + nt * 16 + l15) * 32 + ko_b];
        acc2[nt] = __builtin_amdgcn_mfma_f32_16x16x32_bf16(bfr, af, acc2[nt], 0, 0, 0);
      }
      __syncthreads();
    }
#pragma unroll
    for (int nt = 0; nt < 8; ++nt) {
      const int colb = w * 128 + nt * 16 + quad * 4;
      const float4 bb = *(const float4*)&bu1[colb];
      bf16x4v o;
      o[0] = (bf16_t)gelu_f(acc2[nt][0] + bb.x);
      o[1] = (bf16_t)gelu_f(acc2[nt][1] + bb.y);
      o[2] = (bf16_t)gelu_f(acc2[nt][2] + bb.z);
      o[3] = (bf16_t)gelu_f(acc2[nt][3] + bb.w);
      *(bf16x4v*)&Us[l15 * 520 + colb] = o;
    }
  }
  __syncthreads();

  // ---------------- phase 3: S2 = S1 + Us@Wu2t + bu2 ; out = LN(S2) ----------
  {
    f32x4 acc3[4];
#pragma unroll
    for (int nt = 0; nt < 4; ++nt) acc3[nt] = (f32x4){0.f, 0.f, 0.f, 0.f};

    for (int k0 = 0; k0 < 512; k0 += 32) {
#pragma unroll
      for (int i = 0; i < 4; ++i) {
        const int c = i * 256 + t;
        async16(Wu2t + (size_t)(c >> 2) * 512 + k0 + schunk,
                lB + (size_t)(i * 256 + (t & 192)) * 8);
      }
      __syncthreads();
      const bf16x8 af = *(const bf16x8*)&Us[l15 * 520 + k0 + ko_a];
#pragma unroll
      for (int nt = 0; nt < 4; ++nt) {
        const bf16x8 bfr = *(const bf16x8*)&lB[(w * 64 + nt * 16 + l15) * 32 + ko_b];
        acc3[nt] = __builtin_amdgcn_mfma_f32_16x16x32_bf16(bfr, af, acc3[nt], 0, 0, 0);
      }
      __syncthreads();
    }

    float sum = 0.f, sq = 0.f;
#pragma unroll
    for (int nt = 0; nt < 4; ++nt) {
      const int colb = w * 64 + nt * 16 + quad * 4;
      const float4 bv = *(const float4*)&bu2[colb];
      const bf16x4v s1v = *(const bf16x4v*)&A4s[l15 * 520 + colb];
      float x0 = acc3[nt][0] + bv.x + (float)s1v[0];
      float x1 = acc3[nt][1] + bv.y + (float)s1v[1];
      float x2 = acc3[nt][2] + bv.z + (float)s1v[2];
      float x3 = acc3[nt][3] + bv.w + (float)s1v[3];
      acc3[nt][0] = x0; acc3[nt][1] = x1; acc3[nt][2] = x2; acc3[nt][3] = x3;
      sum += x0 + x1 + x2 + x3;
      sq += x0*x0 + x1*x1 + x2*x2 + x3*x3;
    }
    sum += __shfl_xor(sum, 16, 64); sum += __shfl_xor(sum, 32, 64);
    sq  += __shfl_xor(sq, 16, 64);  sq  += __shfl_xor(sq, 32, 64);
    __syncthreads();   // sSum reuse: prior readers done
    if (lane < 16) { sSum[w][l15] = sum; sSq[w][l15] = sq; }
    __syncthreads();
    const float tot = sSum[0][l15] + sSum[1][l15] + sSum[2][l15] + sSum[3][l15];
    const float tq  = sSq[0][l15] + sSq[1][l15] + sSq[2][l15] + sSq[3][l15];
    const float mean = tot * 0.00390625f;
    const float var = tq * 0.00390625f - mean * mean;
    const float rstd = rsqrtf(var + LN_EPS);
#pragma unroll
    for (int nt = 0; nt < 4; ++nt) {
      const int colb = w * 64 + nt * 16 + quad * 4;
      const float4 gg = *(const float4*)&g2n[colb];
      const float4 bv = *(const float4*)&b2n[colb];
      *(float4*)&out[(size_t)row * 256 + colb] = make_float4(
          (acc3[nt][0]-mean)*rstd*gg.x + bv.x, (acc3[nt][1]-mean)*rstd*gg.y + bv.y,
          (acc3[nt][2]-mean)*rstd*gg.z + bv.z, (acc3[nt][3]-mean)*rstd*gg.w + bv.w);
    }
  }
}

// ---------------------------------------------------------------------------
extern "C" void kernel_launch(void* const* d_in, const int* in_sizes, int n_in,
                              void* d_out, int out_size, void* d_ws, size_t ws_size,
                              hipStream_t stream)
{
  (void)in_sizes; (void)n_in; (void)out_size; (void)ws_size;
  const float* X    = (const float*)d_in[0];
  const float* S    = (const float*)d_in[1];
  const float* Wg   = (const float*)d_in[2];
  const float* Wk   = (const float*)d_in[3];
  const float* Wm1  = (const float*)d_in[4];
  const float* bm1  = (const float*)d_in[5];
  const float* Wm2  = (const float*)d_in[6];
  const float* bm2  = (const float*)d_in[7];
  const float* Wgt1 = (const float*)d_in[8];
  const float* bgt1 = (const float*)d_in[9];
  const float* Wgt2 = (const float*)d_in[10];
  const float* bgt2 = (const float*)d_in[11];
  const float* Wqkv = (const float*)d_in[12];
  const float* bqkv = (const float*)d_in[13];
  const float* Wo   = (const float*)d_in[14];
  const float* bo   = (const float*)d_in[15];
  const float* alng = (const float*)d_in[16];
  const float* alnb = (const float*)d_in[17];
  const float* Wu1  = (const float*)d_in[18];
  const float* bu1  = (const float*)d_in[19];
  const float* Wu2  = (const float*)d_in[20];
  const float* bu2  = (const float*)d_in[21];
  const float* lng  = (const float*)d_in[22];
  const float* lnb  = (const float*)d_in[23];

  char* p = (char*)d_ws;
  auto carve = [&](size_t bytes) { char* r = p; p += bytes; return r; };
  bf16_t* Xb    = (bf16_t*)carve(16777216);   // 32768 x 256
  bf16_t* Sb    = (bf16_t*)carve(2097152);    // 4096 x 256
  bf16_t* W1t   = (bf16_t*)carve(458752);     // 896 x 256
  bf16_t* W2t   = (bf16_t*)carve(262144);     // 256 x 512
  bf16_t* Wqkvt = (bf16_t*)carve(393216);     // 768 x 256
  bf16_t* Wot   = (bf16_t*)carve(131072);     // 256 x 256
  bf16_t* Wu1t  = (bf16_t*)carve(524288);     // 512 x 512
  bf16_t* Wu2t  = (bf16_t*)carve(262144);     // 256 x 512
  bf16_t* h1    = (bf16_t*)carve(33554432);   // 32768 x 512 (msg only)
  u64*    bitmap  = (u64*)carve(2097152);     // 4096 slots x 64 words (zeroed by prep)
  float*  gatelin = (float*)carve(131072);    // 32768 (zeroed by prep, adjacent)
  float*  incom = (float*)carve(4194304);     // 4096 x 256 f32
  bf16_t* qkvb  = (bf16_t*)carve(6291456);    // 4096 x 768 (Q,K used)
  bf16_t* Vt    = (bf16_t*)carve(2097152);    // 2048 x 512 (V transposed per b,h)
  bf16_t* obuf  = (bf16_t*)carve(2097152);    // 4096 x 256
  bf16_t* H     = (bf16_t*)carve(4194304);    // 4096 x 512 (gather output)
  float*  sumg  = (float*)carve(16384);

  // 1. prep (ILP: 4 float4/thread in bulk sections)
  prep_kernel<<<5384, 256, 0, stream>>>(X, S, Wg, Wk, Wm1, Wgt1, Wm2, Wqkv, Wo, Wu1, Wu2,
                                        Xb, Sb, W1t, W2t, Wqkvt, Wot, Wu1t, Wu2t,
                                        (float4*)bitmap);
  // 2. g1 (1792 blocks) + qkv/Vt (384 blocks)
  g1qkv_kernel<<<2176, 256, 0, stream>>>(Xb, W1t, bm1, bgt1, h1,
                                         Wgt2, gatelin, bitmap,
                                         Sb, Wqkvt, bqkv, qkvb, Vt);
  // 3. wave-parallel bitmap-driven aggregate
  gather_kernel<<<4096, 256, 0, stream>>>(h1, gatelin, bgt2, bitmap, H, sumg);
  // 4. G2' (128 blocks) + attention (1024 blocks)
  g2attn_kernel<<<1152, 256, 0, stream>>>(qkvb, Vt, obuf,
                                          H, W2t, bm2, sumg, incom);
  // 5. fused tail: wo+LN1 -> wu1 -> wu2+LN2 (row-local, LDS intermediates)
  tail_kernel<<<256, 256, 0, stream>>>(obuf, Wot, bo, S, incom, alng, alnb,
                                       Wu1t, bu1, Wu2t, bu2, lng, lnb,
                                       (float*)d_out);
}

// Round 14
// 240.125 us; speedup vs baseline: 1.1573x; 1.1573x over previous
//
#include <hip/hip_runtime.h>

typedef __bf16 bf16_t;
typedef __bf16 bf16x8 __attribute__((ext_vector_type(8)));
typedef __bf16 bf16x4v __attribute__((ext_vector_type(4)));
typedef __bf16 bf16x2v __attribute__((ext_vector_type(2)));
typedef float f32x4 __attribute__((ext_vector_type(4)));
typedef unsigned long long u64;

#define LN_EPS 1e-5f

// njuffa's 1-ulp erff (fast path for |a|<=0.921875 is 6 fma)
__device__ __forceinline__ float erf_fast(float a) {
  const float t = fabsf(a);
  const float s = a * a;
  float r;
  if (t > 0.921875f) {
    float u;
    r = fmaf(-1.72853470e-5f, t, 3.83197126e-4f);
    u = fmaf(-3.88396438e-3f, t, 2.42546219e-2f);
    r = fmaf(r, s, u);
    r = fmaf(r, t, 1.06777877e-1f);
    r = fmaf(r, t, -6.37245935e-1f);
    r = fmaf(r, t, -1.28717512e-1f);
    r = fmaf(r, t, t);
    r = 1.0f - __expf(-r);
    r = copysignf(r, a);
  } else {
    r = -5.96761703e-4f;
    r = fmaf(r, s, 4.99119423e-3f);
    r = fmaf(r, s, -2.67681349e-2f);
    r = fmaf(r, s, 1.12819925e-1f);
    r = fmaf(r, s, -3.76125336e-1f);
    r = fmaf(r, s, 1.28379166e-1f);
    r = fmaf(r, a, a);
  }
  return r;
}

__device__ __forceinline__ float gelu_f(float x) {
  const float h = 0.5f * x;
  return fmaf(h, erf_fast(x * 0.70710678118654752f), h);
}

__device__ __forceinline__ void async16(const bf16_t* g, bf16_t* l) {
  __builtin_amdgcn_global_load_lds(
      (const __attribute__((address_space(1))) void*)g,
      (__attribute__((address_space(3))) void*)l, 16, 0, 0);
}

// ---------------------------------------------------------------------------
// prep: X,S -> bf16 ; weights -> transposed bf16 ; zero bitmap+gatelin
// Bulk sections do 4 independent float4 per thread (ILP).
// ---------------------------------------------------------------------------
__global__ __launch_bounds__(256)
void prep_kernel(const float* __restrict__ X, const float* __restrict__ S,
                 const float* __restrict__ Wg, const float* __restrict__ Wk,
                 const float* __restrict__ Wm1, const float* __restrict__ Wgt1,
                 const float* __restrict__ Wm2, const float* __restrict__ Wqkv,
                 const float* __restrict__ Wo, const float* __restrict__ Wu1,
                 const float* __restrict__ Wu2,
                 bf16_t* __restrict__ Xb, bf16_t* __restrict__ Sb,
                 bf16_t* __restrict__ W1t, bf16_t* __restrict__ W2t,
                 bf16_t* __restrict__ Wqkvt, bf16_t* __restrict__ Wot,
                 bf16_t* __restrict__ Wu1t, bf16_t* __restrict__ Wu2t,
                 float4* __restrict__ zbase)
{
  const int bid = blockIdx.x;
  const int t = threadIdx.x;
  if (bid < 2048) {                       // X: 4 float4 per thread
    const int base = bid * 1024 + t;
#pragma unroll
    for (int j = 0; j < 4; ++j) {
      const int i = base + j * 256;
      const float4 v = ((const float4*)X)[i];
      bf16x4v o; o[0]=(bf16_t)v.x; o[1]=(bf16_t)v.y; o[2]=(bf16_t)v.z; o[3]=(bf16_t)v.w;
      ((bf16x4v*)Xb)[i] = o;
    }
  } else if (bid < 2304) {                // S: 4 float4 per thread
    const int base = (bid - 2048) * 1024 + t;
#pragma unroll
    for (int j = 0; j < 4; ++j) {
      const int i = base + j * 256;
      const float4 v = ((const float4*)S)[i];
      bf16x4v o; o[0]=(bf16_t)v.x; o[1]=(bf16_t)v.y; o[2]=(bf16_t)v.z; o[3]=(bf16_t)v.w;
      ((bf16x4v*)Sb)[i] = o;
    }
  } else if (bid < 3200) {                // W1t: 896 rows x 256
    const int n = bid - 2304;
    const int k = t;
    float v;
    if (n < 512)      v = Wm1[k * 512 + n];
    else if (n < 768) v = Wgt1[k * 256 + (n - 512)];
    else if (n < 832) v = Wg[k * 64 + (n - 768)];
    else if (n < 840) v = Wk[k * 8 + (n - 832)];
    else              v = 0.f;
    W1t[n * 256 + k] = (bf16_t)v;
  } else if (bid < 3456) {                // W2t: 256 rows x 512
    const int n = bid - 3200;
    for (int k = t; k < 512; k += 256) W2t[n * 512 + k] = (bf16_t)Wm2[k * 256 + n];
  } else if (bid < 4224) {                // Wqkvt: 768 x 256
    const int n = bid - 3456;
    Wqkvt[n * 256 + t] = (bf16_t)Wqkv[t * 768 + n];
  } else if (bid < 4480) {                // Wot: 256 x 256
    const int n = bid - 4224;
    Wot[n * 256 + t] = (bf16_t)Wo[t * 256 + n];
  } else if (bid < 4992) {                // Wu1t: 512 x 512
    const int n = bid - 4480;
    for (int k = t; k < 512; k += 256) Wu1t[n * 512 + k] = (bf16_t)Wu1[k * 512 + n];
  } else if (bid < 5248) {                // Wu2t: 256 x 512
    const int n = bid - 4992;
    for (int k = t; k < 512; k += 256) Wu2t[n * 512 + k] = (bf16_t)Wu2[k * 256 + n];
  } else {                                // zero bitmap (2MB) + gatelin (128KB)
    const int base = (bid - 5248) * 1024 + t;
#pragma unroll
    for (int j = 0; j < 4; ++j)
      zbase[base + j * 256] = make_float4(0.f, 0.f, 0.f, 0.f);
  }
}

// ---------------------------------------------------------------------------
// g1qkv: merged dispatch.
//   blocks [0,1792): g1 = Xb @ W1t^T with fused routing epilogue
//     (128x128 tile, 4 waves, wave 64x64, acc[4][4]; (256,2) proven optimum)
//   blocks [1792,2176): qkv = Sb @ Wqkvt^T + bqkv (depends only on prep).
// XOR-swizzled LDS in g1 path (slot s of row r holds chunk s^(r&3)).
// ---------------------------------------------------------------------------
__global__ __launch_bounds__(256, 2)
void g1qkv_kernel(const bf16_t* __restrict__ A,
                  const bf16_t* __restrict__ Bt,
                  const float* __restrict__ bias, const float* __restrict__ bias2,
                  bf16_t* __restrict__ h1,
                  const float* __restrict__ wgt2, float* __restrict__ gatelin,
                  u64* __restrict__ bitmap,
                  const bf16_t* __restrict__ Sb, const bf16_t* __restrict__ Wqkvt,
                  const float* __restrict__ bqkv, bf16_t* __restrict__ qkvb,
                  bf16_t* __restrict__ Vt)
{
  const int bid = blockIdx.x;
  const int t = threadIdx.x;
  const int w = t >> 6;
  const int lane = t & 63;
  const int wr = w >> 1, wc = w & 1;
  const int quad = lane >> 4, l15 = lane & 15;

  __shared__ bf16_t lA[128 * 32];
  __shared__ bf16_t lB[128 * 32];
  __shared__ float sWg[256];
  __shared__ int sKi[128];

  if (bid >= 1792) {
    // ---------------- qkv path (64-row tile) -------
    const int id = bid - 1792;
    const int m0 = (id & 63) * 64;
    const int n0 = (id >> 6) * 128;

    f32x4 acc[2][4];
#pragma unroll
    for (int mt = 0; mt < 2; ++mt)
#pragma unroll
      for (int nt = 0; nt < 4; ++nt)
        acc[mt][nt] = (f32x4){0.f, 0.f, 0.f, 0.f};

    for (int k0 = 0; k0 < 256; k0 += 32) {
      async16(Sb + (size_t)(m0 + (t >> 2)) * 256 + k0 + (t & 3) * 8,
              lA + (size_t)(t & 192) * 8);
#pragma unroll
      for (int i = 0; i < 2; ++i) {
        const int c = i * 256 + t;
        async16(Wqkvt + (size_t)(n0 + (c >> 2)) * 256 + k0 + (c & 3) * 8,
                lB + (size_t)(i * 256 + (t & 192)) * 8);
      }
      __syncthreads();
      bf16x8 af[2], bfr[4];
      const int ko = quad * 8;
#pragma unroll
      for (int mt = 0; mt < 2; ++mt)
        af[mt] = *(const bf16x8*)&lA[(wr * 32 + mt * 16 + l15) * 32 + ko];
#pragma unroll
      for (int nt = 0; nt < 4; ++nt)
        bfr[nt] = *(const bf16x8*)&lB[(wc * 64 + nt * 16 + l15) * 32 + ko];
#pragma unroll
      for (int mt = 0; mt < 2; ++mt)
#pragma unroll
        for (int nt = 0; nt < 4; ++nt)
          acc[mt][nt] = __builtin_amdgcn_mfma_f32_16x16x32_bf16(bfr[nt], af[mt], acc[mt][nt], 0, 0, 0);
      __syncthreads();
    }

    if (n0 < 512) {
      // Q/K: row-major qkvb (ldc=768)
#pragma unroll
      for (int mt = 0; mt < 2; ++mt) {
        const int row = m0 + wr * 32 + mt * 16 + l15;
#pragma unroll
        for (int nt = 0; nt < 4; ++nt) {
          const int colb = n0 + wc * 64 + nt * 16 + quad * 4;
          const float4 bb = *(const float4*)&bqkv[colb];
          bf16x4v o; o[0]=(bf16_t)(acc[mt][nt][0]+bb.x); o[1]=(bf16_t)(acc[mt][nt][1]+bb.y);
          o[2]=(bf16_t)(acc[mt][nt][2]+bb.z); o[3]=(bf16_t)(acc[mt][nt][3]+bb.w);
          *(bf16x4v*)&qkvb[(size_t)row * 768 + colb] = o;
        }
      }
    } else {
      // V: transposed -> Vt[((b*8+h)*32 + dh)*512 + key]
#pragma unroll
      for (int mt = 0; mt < 2; ++mt) {
        const int row = m0 + wr * 32 + mt * 16 + l15;
        const int b = row >> 9, key = row & 511;
#pragma unroll
        for (int nt = 0; nt < 4; ++nt) {
          const int colb = n0 + wc * 64 + nt * 16 + quad * 4;
          const int c = colb - 512;
          const int h2 = c >> 5, dh = c & 31;
          const float4 bb = *(const float4*)&bqkv[colb];
          bf16_t* vb = Vt + ((size_t)(b * 8 + h2) * 32 + dh) * 512 + key;
          vb[0]   = (bf16_t)(acc[mt][nt][0] + bb.x);
          vb[512] = (bf16_t)(acc[mt][nt][1] + bb.y);
          vb[1024]= (bf16_t)(acc[mt][nt][2] + bb.z);
          vb[1536]= (bf16_t)(acc[mt][nt][3] + bb.w);
        }
      }
    }
    return;
  }

  // ---------------- g1 path (proven 44.9us kernel) -------
  const int m0 = (bid & 255) * 128;
  const int by = bid >> 8;
  const int n0 = by * 128;

  if (by >= 4 && by < 6) sWg[t] = wgt2[t];

  f32x4 acc[4][4];
#pragma unroll
  for (int mt = 0; mt < 4; ++mt)
#pragma unroll
    for (int nt = 0; nt < 4; ++nt)
      acc[mt][nt] = (f32x4){0.f, 0.f, 0.f, 0.f};

  const int srow = t >> 2;                             // row within 64-row half
  const int schunk = ((t & 3) ^ (srow & 3)) * 8;       // swizzled source chunk
  const int ko = ((quad ^ (l15 & 3)) << 3);            // swizzled read offset

  for (int k0 = 0; k0 < 256; k0 += 32) {
#pragma unroll
    for (int i = 0; i < 2; ++i) {
      const int row = i * 64 + srow;
      async16(A + (size_t)(m0 + row) * 256 + k0 + schunk,
              lA + (size_t)(i * 256 + (t & 192)) * 8);
      async16(Bt + (size_t)(n0 + row) * 256 + k0 + schunk,
              lB + (size_t)(i * 256 + (t & 192)) * 8);
    }
    __syncthreads();
    bf16x8 af[4], bfr[4];
#pragma unroll
    for (int mt = 0; mt < 4; ++mt)
      af[mt] = *(const bf16x8*)&lA[(wr * 64 + mt * 16 + l15) * 32 + ko];
#pragma unroll
    for (int nt = 0; nt < 4; ++nt)
      bfr[nt] = *(const bf16x8*)&lB[(wc * 64 + nt * 16 + l15) * 32 + ko];
#pragma unroll
    for (int mt = 0; mt < 4; ++mt)
#pragma unroll
      for (int nt = 0; nt < 4; ++nt)
        acc[mt][nt] = __builtin_amdgcn_mfma_f32_16x16x32_bf16(bfr[nt], af[mt], acc[mt][nt], 0, 0, 0);
    __syncthreads();
  }

  if (by < 4) {
    // msg: gelu(v + bm1) -> h1 bf16, ldc = 512
#pragma unroll
    for (int mt = 0; mt < 4; ++mt) {
      const int row = m0 + wr * 64 + mt * 16 + l15;
#pragma unroll
      for (int nt = 0; nt < 4; ++nt) {
        const int colb = n0 + wc * 64 + nt * 16 + quad * 4;
        const float4 bb = *(const float4*)&bias[colb];
        bf16x4v o;
        o[0] = (bf16_t)gelu_f(acc[mt][nt][0] + bb.x);
        o[1] = (bf16_t)gelu_f(acc[mt][nt][1] + bb.y);
        o[2] = (bf16_t)gelu_f(acc[mt][nt][2] + bb.z);
        o[3] = (bf16_t)gelu_f(acc[mt][nt][3] + bb.w);
        *(bf16x4v*)&h1[(size_t)row * 512 + colb] = o;
      }
    }
  } else if (by < 6) {
    // gate strips: partial dot of gelu(g1) with Wgt2 -> atomicAdd gatelin
#pragma unroll
    for (int mt = 0; mt < 4; ++mt) {
      const int row = m0 + wr * 64 + mt * 16 + l15;
      float part = 0.f;
#pragma unroll
      for (int nt = 0; nt < 4; ++nt) {
        const int colb = n0 + wc * 64 + nt * 16 + quad * 4;
        const int c = colb - 512;
        const float4 bb = *(const float4*)&bias2[c];
        part = fmaf(gelu_f(acc[mt][nt][0] + bb.x), sWg[c + 0], part);
        part = fmaf(gelu_f(acc[mt][nt][1] + bb.y), sWg[c + 1], part);
        part = fmaf(gelu_f(acc[mt][nt][2] + bb.z), sWg[c + 2], part);
        part = fmaf(gelu_f(acc[mt][nt][3] + bb.w), sWg[c + 3], part);
      }
      part += __shfl_xor(part, 16, 64);
      part += __shfl_xor(part, 32, 64);
      if (lane < 16) atomicAdd(&gatelin[row], part);
    }
  } else {
    // logit strip: argmax(g)*8 + argmax(k) -> bitmap
    int bi[4];
#pragma unroll
    for (int mt = 0; mt < 4; ++mt) {
      if (wc == 0) {
        float mv = -1e30f; int mi = 0;
#pragma unroll
        for (int nt = 0; nt < 4; ++nt)
#pragma unroll
          for (int j = 0; j < 4; ++j) {
            const int gc = nt * 16 + quad * 4 + j;
            const float v = acc[mt][nt][j];
            if (v > mv || (v == mv && gc < mi)) { mv = v; mi = gc; }
          }
#pragma unroll
        for (int off = 16; off <= 32; off <<= 1) {
          const float ov = __shfl_xor(mv, off, 64);
          const int oi = __shfl_xor(mi, off, 64);
          if (ov > mv || (ov == mv && oi < mi)) { mv = ov; mi = oi; }
        }
        bi[mt] = mi;
      } else {
        float mv = -1e30f; int mi = 0;
        if (quad < 2) {
#pragma unroll
          for (int j = 0; j < 4; ++j) {
            const int kc = quad * 4 + j;
            const float v = acc[mt][0][j];
            if (v > mv || (v == mv && kc < mi)) { mv = v; mi = kc; }
          }
        }
#pragma unroll
        for (int off = 16; off <= 32; off <<= 1) {
          const float ov = __shfl_xor(mv, off, 64);
          const int oi = __shfl_xor(mi, off, 64);
          if (ov > mv || (ov == mv && oi < mi)) { mv = ov; mi = oi; }
        }
        if (lane < 16) sKi[wr * 64 + mt * 16 + l15] = mi;
      }
    }
    __syncthreads();
    if (wc == 0 && lane < 16) {
#pragma unroll
      for (int mt = 0; mt < 4; ++mt) {
        const int rl = wr * 64 + mt * 16 + l15;
        const int row = m0 + rl;
        const int idx = bi[mt] * 8 + sKi[rl];
        const int b = row >> 12, tok = row & 4095;
        atomicOr(&bitmap[(size_t)(b * 512 + idx) * 64 + (tok >> 6)],
                 1ull << (tok & 63));
      }
    }
  }
}

// ---------------------------------------------------------------------------
// gather: block per (b,slot); WAVE-PARALLEL bitmap walk.
//   wave w owns bitmap words [16w, 16w+16) -> 4 independent token chains.
//   lane owns 8 columns (bf16x8 coalesced row read); 1-deep manual prefetch.
//   Cross-wave reduce via LDS.
// ---------------------------------------------------------------------------
__global__ __launch_bounds__(256)
void gather_kernel(const bf16_t* __restrict__ h1, const float* __restrict__ gatelin,
                   const float* __restrict__ bgt2, const u64* __restrict__ bitmap,
                   bf16_t* __restrict__ H, float* __restrict__ sumg)
{
  const int bs = blockIdx.x;
  const int b = bs >> 9;
  const int t = threadIdx.x;
  const int w = t >> 6, lane = t & 63;
  __shared__ u64 sw[64];
  __shared__ float pa[4][512];
  __shared__ float psg[4];
  if (t < 64) sw[t] = bitmap[(size_t)bs * 64 + t];
  __syncthreads();
  const float bg = bgt2[0];

  float a[8];
#pragma unroll
  for (int j = 0; j < 8; ++j) a[j] = 0.f;
  float sg = 0.f;

  int wd = w * 16;
  const int wend = wd + 16;
  u64 word = sw[wd];
  auto pop = [&]() -> int {
    while (word == 0) {
      if (++wd >= wend) return -1;
      word = sw[wd];
    }
    const int bit = __builtin_ctzll(word);
    word &= word - 1;
    return (b << 12) + (wd << 6) + bit;
  };

  int l0 = pop();
  float gl0 = 0.f;
  bf16x8 hv0 = {};
  if (l0 >= 0) {
    gl0 = gatelin[l0];
    hv0 = *(const bf16x8*)&h1[(size_t)l0 * 512 + lane * 8];
  }
  while (l0 >= 0) {
    const int l1 = pop();
    float gl1 = 0.f;
    bf16x8 hv1 = {};
    if (l1 >= 0) {                       // prefetch next token while consuming cur
      gl1 = gatelin[l1];
      hv1 = *(const bf16x8*)&h1[(size_t)l1 * 512 + lane * 8];
    }
    const float g = 1.0f / (1.0f + __expf(-(gl0 + bg)));
#pragma unroll
    for (int j = 0; j < 8; ++j) a[j] = fmaf(g, (float)hv0[j], a[j]);
    sg += g;
    l0 = l1; gl0 = gl1; hv0 = hv1;
  }

#pragma unroll
  for (int j = 0; j < 8; ++j) pa[w][lane * 8 + j] = a[j];
  if (lane == 0) psg[w] = sg;
  __syncthreads();

  const int c = t * 2;
  const float r0 = pa[0][c] + pa[1][c] + pa[2][c] + pa[3][c];
  const float r1 = pa[0][c + 1] + pa[1][c + 1] + pa[2][c + 1] + pa[3][c + 1];
  bf16x2v o; o[0] = (bf16_t)r0; o[1] = (bf16_t)r1;
  *(bf16x2v*)&H[(size_t)bs * 512 + c] = o;
  if (t == 0) sumg[bs] = psg[0] + psg[1] + psg[2] + psg[3];
}

// ---------------------------------------------------------------------------
// g2attn: merged dispatch.
//   blocks [0,128): G2' (incoming = H@Wm2 + sumg*bm2, f32, 64-row tiles)
//   blocks [128,1152): fused slot attention (b, h, 32-query chunk), 4 waves.
// ---------------------------------------------------------------------------
__global__ __launch_bounds__(256)
void g2attn_kernel(const bf16_t* __restrict__ qkv, const bf16_t* __restrict__ Vt,
                   bf16_t* __restrict__ obuf,
                   const bf16_t* __restrict__ H, const bf16_t* __restrict__ W2t,
                   const float* __restrict__ bm2, const float* __restrict__ sumg,
                   float* __restrict__ incom)
{
  const int bid = blockIdx.x;
  const int t = threadIdx.x;
  const int w = t >> 6, lane = t & 63;
  const int quad = lane >> 4, l15 = lane & 15;

  __shared__ bf16_t sP[32 * 520];
  __shared__ float sL[32];

  if (bid < 128) {
    // ---------------- G2' path (64-row tile) ------
    const int wr = w >> 1, wc = w & 1;
    const int m0 = (bid & 63) * 64;
    const int n0 = (bid >> 6) * 128;
    bf16_t* lA = sP;                 // 64*32 elems
    bf16_t* lB = sP + 64 * 32;       // 128*32 elems

    f32x4 acc[2][4];
#pragma unroll
    for (int mt = 0; mt < 2; ++mt)
#pragma unroll
      for (int nt = 0; nt < 4; ++nt)
        acc[mt][nt] = (f32x4){0.f, 0.f, 0.f, 0.f};

    for (int k0 = 0; k0 < 512; k0 += 32) {
      async16(H + (size_t)(m0 + (t >> 2)) * 512 + k0 + (t & 3) * 8,
              lA + (size_t)(t & 192) * 8);
#pragma unroll
      for (int i = 0; i < 2; ++i) {
        const int c = i * 256 + t;
        async16(W2t + (size_t)(n0 + (c >> 2)) * 512 + k0 + (c & 3) * 8,
                lB + (size_t)(i * 256 + (t & 192)) * 8);
      }
      __syncthreads();
      bf16x8 af[2], bfr[4];
      const int ko = quad * 8;
#pragma unroll
      for (int mt = 0; mt < 2; ++mt)
        af[mt] = *(const bf16x8*)&lA[(wr * 32 + mt * 16 + l15) * 32 + ko];
#pragma unroll
      for (int nt = 0; nt < 4; ++nt)
        bfr[nt] = *(const bf16x8*)&lB[(wc * 64 + nt * 16 + l15) * 32 + ko];
#pragma unroll
      for (int mt = 0; mt < 2; ++mt)
#pragma unroll
        for (int nt = 0; nt < 4; ++nt)
          acc[mt][nt] = __builtin_amdgcn_mfma_f32_16x16x32_bf16(bfr[nt], af[mt], acc[mt][nt], 0, 0, 0);
      __syncthreads();
    }

#pragma unroll
    for (int mt = 0; mt < 2; ++mt) {
      const int row = m0 + wr * 32 + mt * 16 + l15;
      const float gt = sumg[row];
#pragma unroll
      for (int nt = 0; nt < 4; ++nt) {
        const int colb = n0 + wc * 64 + nt * 16 + quad * 4;
        const float4 bb = *(const float4*)&bm2[colb];
        *(float4*)&incom[(size_t)row * 256 + colb] =
            make_float4(fmaf(gt, bb.x, acc[mt][nt][0]), fmaf(gt, bb.y, acc[mt][nt][1]),
                        fmaf(gt, bb.z, acc[mt][nt][2]), fmaf(gt, bb.w, acc[mt][nt][3]));
      }
    }
    return;
  }

  // ---------------- attention path ------
  const int abid = bid - 128;
  const int qc = abid & 15;
  const int h = (abid >> 4) & 7;
  const int b = abid >> 7;

  bf16x8 qf[2];
#pragma unroll
  for (int mt = 0; mt < 2; ++mt) {
    const int row = b * 512 + qc * 32 + mt * 16 + l15;
    qf[mt] = *(const bf16x8*)&qkv[(size_t)row * 768 + h * 32 + quad * 8];
  }
  const float scale = 0.17677669529663687f;  // 1/sqrt(32)
  for (int kt = w; kt < 32; kt += 4) {
    const int key = b * 512 + kt * 16 + l15;
    const bf16x8 kf = *(const bf16x8*)&qkv[(size_t)key * 768 + 256 + h * 32 + quad * 8];
#pragma unroll
    for (int mt = 0; mt < 2; ++mt) {
      f32x4 c = (f32x4){0.f, 0.f, 0.f, 0.f};
      c = __builtin_amdgcn_mfma_f32_16x16x32_bf16(qf[mt], kf, c, 0, 0, 0);
#pragma unroll
      for (int r = 0; r < 4; ++r)
        sP[(mt * 16 + quad * 4 + r) * 520 + kt * 16 + l15] = (bf16_t)(c[r] * scale);
    }
  }
  __syncthreads();

#pragma unroll
  for (int ri = 0; ri < 8; ++ri) {
    const int row = w * 8 + ri;
    const bf16x8 sv = *(const bf16x8*)&sP[row * 520 + lane * 8];
    float sval[8];
    float mx = -1e30f;
#pragma unroll
    for (int j = 0; j < 8; ++j) { sval[j] = (float)sv[j]; mx = fmaxf(mx, sval[j]); }
#pragma unroll
    for (int off = 32; off; off >>= 1) mx = fmaxf(mx, __shfl_xor(mx, off, 64));
    float sum = 0.f;
    bf16x8 pv;
#pragma unroll
    for (int j = 0; j < 8; ++j) { const float e = __expf(sval[j] - mx); sum += e; pv[j] = (bf16_t)e; }
#pragma unroll
    for (int off = 32; off; off >>= 1) sum += __shfl_xor(sum, off, 64);
    *(bf16x8*)&sP[row * 520 + lane * 8] = pv;
    if (lane == 0) sL[row] = sum;
  }
  __syncthreads();

  // PV: wave (wq, wd) computes O[qc*32 + wq*16 + q][wd*16 + dh-range]
  const int wq = w >> 1, wd = w & 1;
  const bf16_t* vbase = Vt + ((size_t)(b * 8 + h) * 32 + wd * 16 + l15) * 512;
  const bf16_t* pbase = &sP[(wq * 16 + l15) * 520];
  f32x4 oacc = (f32x4){0.f, 0.f, 0.f, 0.f};
#pragma unroll
  for (int kt = 0; kt < 16; ++kt) {
    const bf16x8 af = *(const bf16x8*)&pbase[kt * 32 + quad * 8];
    const bf16x8 vf = *(const bf16x8*)&vbase[kt * 32 + quad * 8];
    oacc = __builtin_amdgcn_mfma_f32_16x16x32_bf16(vf, af, oacc, 0, 0, 0);
  }
  const int rowq = wq * 16 + l15;
  const float inv = 1.0f / sL[rowq];
  bf16x4v o;
#pragma unroll
  for (int r = 0; r < 4; ++r) o[r] = (bf16_t)(oacc[r] * inv);
  *(bf16x4v*)&obuf[(size_t)(b * 512 + qc * 32 + rowq) * 256 + h * 32 + wd * 16 + quad * 4] = o;
}

// ---------------------------------------------------------------------------
// tail: fused wo_ln1 + wu1 + wu2_ln2 (row-local chain, LDS intermediates).
// Block = 16 rows, 256 threads, 4 waves.
// ---------------------------------------------------------------------------
__global__ __launch_bounds__(256)
void tail_kernel(const bf16_t* __restrict__ obuf, const bf16_t* __restrict__ Wot,
                 const float* __restrict__ bo, const float* __restrict__ S,
                 const float* __restrict__ incom,
                 const float* __restrict__ g1n, const float* __restrict__ b1n,
                 const bf16_t* __restrict__ Wu1t, const float* __restrict__ bu1,
                 const bf16_t* __restrict__ Wu2t, const float* __restrict__ bu2,
                 const float* __restrict__ g2n, const float* __restrict__ b2n,
                 float* __restrict__ out)
{
  const int m0 = blockIdx.x * 16;
  const int t = threadIdx.x;
  const int w = t >> 6, lane = t & 63;
  const int quad = lane >> 4, l15 = lane & 15;

  __shared__ bf16_t lB[512 * 32];     // 32KB staging (phases use a prefix)
  __shared__ bf16_t lA[16 * 32];      // obuf staging (phase 1)
  __shared__ bf16_t A4s[16 * 520];    // [S1|incom] bf16, padded stride
  __shared__ bf16_t Us[16 * 520];     // hidden bf16, padded stride
  __shared__ float sSum[4][16];
  __shared__ float sSq[4][16];

  const int schunk = ((t & 3) ^ ((t >> 2) & 3)) * 8;   // swizzled B source chunk
  const int ko_b = ((quad ^ (l15 & 3)) << 3);          // swizzled B read offset
  const int ko_a = quad * 8;                           // plain A read offset
  const int row = m0 + l15;

  // ---------------- phase 1: S1 = LN(S + obuf@Wot + bo) ----------------
  {
    f32x4 acc[4];
#pragma unroll
    for (int nt = 0; nt < 4; ++nt) acc[nt] = (f32x4){0.f, 0.f, 0.f, 0.f};

    for (int k0 = 0; k0 < 256; k0 += 32) {
      if (t < 64)
        async16(obuf + (size_t)(m0 + (t >> 2)) * 256 + k0 + (t & 3) * 8, lA);
#pragma unroll
      for (int i = 0; i < 4; ++i) {
        const int c = i * 256 + t;
        async16(Wot + (size_t)(c >> 2) * 256 + k0 + schunk,
                lB + (size_t)(i * 256 + (t & 192)) * 8);
      }
      __syncthreads();
      const bf16x8 af = *(const bf16x8*)&lA[l15 * 32 + ko_a];
#pragma unroll
      for (int nt = 0; nt < 4; ++nt) {
        const bf16x8 bfr = *(const bf16x8*)&lB[(w * 64 + nt * 16 + l15) * 32 + ko_b];
        acc[nt] = __builtin_amdgcn_mfma_f32_16x16x32_bf16(bfr, af, acc[nt], 0, 0, 0);
      }
      __syncthreads();
    }

    float sum = 0.f, sq = 0.f;
#pragma unroll
    for (int nt = 0; nt < 4; ++nt) {
      const int colb = w * 64 + nt * 16 + quad * 4;
      const float4 bv = *(const float4*)&bo[colb];
      const float4 sv = *(const float4*)&S[(size_t)row * 256 + colb];
      float x0 = acc[nt][0] + bv.x + sv.x, x1 = acc[nt][1] + bv.y + sv.y;
      float x2 = acc[nt][2] + bv.z + sv.z, x3 = acc[nt][3] + bv.w + sv.w;
      acc[nt][0] = x0; acc[nt][1] = x1; acc[nt][2] = x2; acc[nt][3] = x3;
      sum += x0 + x1 + x2 + x3;
      sq += x0*x0 + x1*x1 + x2*x2 + x3*x3;
    }
    sum += __shfl_xor(sum, 16, 64); sum += __shfl_xor(sum, 32, 64);
    sq  += __shfl_xor(sq, 16, 64);  sq  += __shfl_xor(sq, 32, 64);
    if (lane < 16) { sSum[w][l15] = sum; sSq[w][l15] = sq; }
    __syncthreads();
    const float tot = sSum[0][l15] + sSum[1][l15] + sSum[2][l15] + sSum[3][l15];
    const float tq  = sSq[0][l15] + sSq[1][l15] + sSq[2][l15] + sSq[3][l15];
    const float mean = tot * 0.00390625f;
    const float var = tq * 0.00390625f - mean * mean;
    const float rstd = rsqrtf(var + LN_EPS);
#pragma unroll
    for (int nt = 0; nt < 4; ++nt) {
      const int colb = w * 64 + nt * 16 + quad * 4;
      const float4 gg = *(const float4*)&g1n[colb];
      const float4 bv = *(const float4*)&b1n[colb];
      bf16x4v yb;
      yb[0] = (bf16_t)((acc[nt][0]-mean)*rstd*gg.x + bv.x);
      yb[1] = (bf16_t)((acc[nt][1]-mean)*rstd*gg.y + bv.y);
      yb[2] = (bf16_t)((acc[nt][2]-mean)*rstd*gg.z + bv.z);
      yb[3] = (bf16_t)((acc[nt][3]-mean)*rstd*gg.w + bv.w);
      *(bf16x4v*)&A4s[l15 * 520 + colb] = yb;
      const float4 ic = *(const float4*)&incom[(size_t)row * 256 + colb];
      bf16x4v ib; ib[0]=(bf16_t)ic.x; ib[1]=(bf16_t)ic.y; ib[2]=(bf16_t)ic.z; ib[3]=(bf16_t)ic.w;
      *(bf16x4v*)&A4s[l15 * 520 + 256 + colb] = ib;
    }
  }
  __syncthreads();

  // ---------------- phase 2: h = gelu(A4s @ Wu1t + bu1) -> Us ----------------
  {
    f32x4 acc2[8];
#pragma unroll
    for (int nt = 0; nt < 8; ++nt) acc2[nt] = (f32x4){0.f, 0.f, 0.f, 0.f};

    for (int k0 = 0; k0 < 512; k0 += 32) {
#pragma unroll
      for (int i = 0; i < 8; ++i) {
        const int c = i * 256 + t;
        async16(Wu1t + (size_t)(c >> 2) * 512 + k0 + schunk,
                lB + (size_t)(i * 256 + (t & 192)) * 8);
      }
      __syncthreads();
      const bf16x8 af = *(const bf16x8*)&A4s[l15 * 520 + k0 + ko_a];
#pragma unroll
      for (int nt = 0; nt < 8; ++nt) {
        const bf16x8 bfr = *(const bf16x8*)&lB[(w * 128 + nt * 16 + l15) * 32 + ko_b];
        acc2[nt] = __builtin_amdgcn_mfma_f32_16x16x32_bf16(bfr, af, acc2[nt], 0, 0, 0);
      }
      __syncthreads();
    }
#pragma unroll
    for (int nt = 0; nt < 8; ++nt) {
      const int colb = w * 128 + nt * 16 + quad * 4;
      const float4 bb = *(const float4*)&bu1[colb];
      bf16x4v o;
      o[0] = (bf16_t)gelu_f(acc2[nt][0] + bb.x);
      o[1] = (bf16_t)gelu_f(acc2[nt][1] + bb.y);
      o[2] = (bf16_t)gelu_f(acc2[nt][2] + bb.z);
      o[3] = (bf16_t)gelu_f(acc2[nt][3] + bb.w);
      *(bf16x4v*)&Us[l15 * 520 + colb] = o;
    }
  }
  __syncthreads();

  // ---------------- phase 3: S2 = S1 + Us@Wu2t + bu2 ; out = LN(S2) ----------
  {
    f32x4 acc3[4];
#pragma unroll
    for (int nt = 0; nt < 4; ++nt) acc3[nt] = (f32x4){0.f, 0.f, 0.f, 0.f};

    for (int k0 = 0; k0 < 512; k0 += 32) {
#pragma unroll
      for (int i = 0; i < 4; ++i) {
        const int c = i * 256 + t;
        async16(Wu2t + (size_t)(c >> 2) * 512 + k0 + schunk,
                lB + (size_t)(i * 256 + (t & 192)) * 8);
      }
      __syncthreads();
      const bf16x8 af = *(const bf16x8*)&Us[l15 * 520 + k0 + ko_a];
#pragma unroll
      for (int nt = 0; nt < 4; ++nt) {
        const bf16x8 bfr = *(const bf16x8*)&lB[(w * 64 + nt * 16 + l15) * 32 + ko_b];
        acc3[nt] = __builtin_amdgcn_mfma_f32_16x16x32_bf16(bfr, af, acc3[nt], 0, 0, 0);
      }
      __syncthreads();
    }

    float sum = 0.f, sq = 0.f;
#pragma unroll
    for (int nt = 0; nt < 4; ++nt) {
      const int colb = w * 64 + nt * 16 + quad * 4;
      const float4 bv = *(const float4*)&bu2[colb];
      const bf16x4v s1v = *(const bf16x4v*)&A4s[l15 * 520 + colb];
      float x0 = acc3[nt][0] + bv.x + (float)s1v[0];
      float x1 = acc3[nt][1] + bv.y + (float)s1v[1];
      float x2 = acc3[nt][2] + bv.z + (float)s1v[2];
      float x3 = acc3[nt][3] + bv.w + (float)s1v[3];
      acc3[nt][0] = x0; acc3[nt][1] = x1; acc3[nt][2] = x2; acc3[nt][3] = x3;
      sum += x0 + x1 + x2 + x3;
      sq += x0*x0 + x1*x1 + x2*x2 + x3*x3;
    }
    sum += __shfl_xor(sum, 16, 64); sum += __shfl_xor(sum, 32, 64);
    sq  += __shfl_xor(sq, 16, 64);  sq  += __shfl_xor(sq, 32, 64);
    __syncthreads();   // sSum reuse: prior readers done
    if (lane < 16) { sSum[w][l15] = sum; sSq[w][l15] = sq; }
    __syncthreads();
    const float tot = sSum[0][l15] + sSum[1][l15] + sSum[2][l15] + sSum[3][l15];
    const float tq  = sSq[0][l15] + sSq[1][l15] + sSq[2][l15] + sSq[3][l15];
    const float mean = tot * 0.00390625f;
    const float var = tq * 0.00390625f - mean * mean;
    const float rstd = rsqrtf(var + LN_EPS);
#pragma unroll
    for (int nt = 0; nt < 4; ++nt) {
      const int colb = w * 64 + nt * 16 + quad * 4;
      const float4 gg = *(const float4*)&g2n[colb];
      const float4 bv = *(const float4*)&b2n[colb];
      *(float4*)&out[(size_t)row * 256 + colb] = make_float4(
          (acc3[nt][0]-mean)*rstd*gg.x + bv.x, (acc3[nt][1]-mean)*rstd*gg.y + bv.y,
          (acc3[nt][2]-mean)*rstd*gg.z + bv.z, (acc3[nt][3]-mean)*rstd*gg.w + bv.w);
    }
  }
}

// ---------------------------------------------------------------------------
extern "C" void kernel_launch(void* const* d_in, const int* in_sizes, int n_in,
                              void* d_out, int out_size, void* d_ws, size_t ws_size,
                              hipStream_t stream)
{
  (void)in_sizes; (void)n_in; (void)out_size; (void)ws_size;
  const float* X    = (const float*)d_in[0];
  const float* S    = (const float*)d_in[1];
  const float* Wg   = (const float*)d_in[2];
  const float* Wk   = (const float*)d_in[3];
  const float* Wm1  = (const float*)d_in[4];
  const float* bm1  = (const float*)d_in[5];
  const float* Wm2  = (const float*)d_in[6];
  const float* bm2  = (const float*)d_in[7];
  const float* Wgt1 = (const float*)d_in[8];
  const float* bgt1 = (const float*)d_in[9];
  const float* Wgt2 = (const float*)d_in[10];
  const float* bgt2 = (const float*)d_in[11];
  const float* Wqkv = (const float*)d_in[12];
  const float* bqkv = (const float*)d_in[13];
  const float* Wo   = (const float*)d_in[14];
  const float* bo   = (const float*)d_in[15];
  const float* alng = (const float*)d_in[16];
  const float* alnb = (const float*)d_in[17];
  const float* Wu1  = (const float*)d_in[18];
  const float* bu1  = (const float*)d_in[19];
  const float* Wu2  = (const float*)d_in[20];
  const float* bu2  = (const float*)d_in[21];
  const float* lng  = (const float*)d_in[22];
  const float* lnb  = (const float*)d_in[23];

  char* p = (char*)d_ws;
  auto carve = [&](size_t bytes) { char* r = p; p += bytes; return r; };
  bf16_t* Xb    = (bf16_t*)carve(16777216);   // 32768 x 256
  bf16_t* Sb    = (bf16_t*)carve(2097152);    // 4096 x 256
  bf16_t* W1t   = (bf16_t*)carve(458752);     // 896 x 256
  bf16_t* W2t   = (bf16_t*)carve(262144);     // 256 x 512
  bf16_t* Wqkvt = (bf16_t*)carve(393216);     // 768 x 256
  bf16_t* Wot   = (bf16_t*)carve(131072);     // 256 x 256
  bf16_t* Wu1t  = (bf16_t*)carve(524288);     // 512 x 512
  bf16_t* Wu2t  = (bf16_t*)carve(262144);     // 256 x 512
  bf16_t* h1    = (bf16_t*)carve(33554432);   // 32768 x 512 (msg only)
  u64*    bitmap  = (u64*)carve(2097152);     // 4096 slots x 64 words (zeroed by prep)
  float*  gatelin = (float*)carve(131072);    // 32768 (zeroed by prep, adjacent)
  float*  incom = (float*)carve(4194304);     // 4096 x 256 f32
  bf16_t* qkvb  = (bf16_t*)carve(6291456);    // 4096 x 768 (Q,K used)
  bf16_t* Vt    = (bf16_t*)carve(2097152);    // 2048 x 512 (V transposed per b,h)
  bf16_t* obuf  = (bf16_t*)carve(2097152);    // 4096 x 256
  bf16_t* H     = (bf16_t*)carve(4194304);    // 4096 x 512 (gather output)
  float*  sumg  = (float*)carve(16384);

  // 1. prep (ILP: 4 float4/thread in bulk sections)
  prep_kernel<<<5384, 256, 0, stream>>>(X, S, Wg, Wk, Wm1, Wgt1, Wm2, Wqkv, Wo, Wu1, Wu2,
                                        Xb, Sb, W1t, W2t, Wqkvt, Wot, Wu1t, Wu2t,
                                        (float4*)bitmap);
  // 2. g1 (1792 blocks) + qkv/Vt (384 blocks)
  g1qkv_kernel<<<2176, 256, 0, stream>>>(Xb, W1t, bm1, bgt1, h1,
                                         Wgt2, gatelin, bitmap,
                                         Sb, Wqkvt, bqkv, qkvb, Vt);
  // 3. wave-parallel bitmap-driven aggregate
  gather_kernel<<<4096, 256, 0, stream>>>(h1, gatelin, bgt2, bitmap, H, sumg);
  // 4. G2' (128 blocks) + attention (1024 blocks)
  g2attn_kernel<<<1152, 256, 0, stream>>>(qkvb, Vt, obuf,
                                          H, W2t, bm2, sumg, incom);
  // 5. fused tail: wo+LN1 -> wu1 -> wu2+LN2 (row-local, LDS intermediates)
  tail_kernel<<<256, 256, 0, stream>>>(obuf, Wot, bo, S, incom, alng, alnb,
                                       Wu1t, bu1, Wu2t, bu2, lng, lnb,
                                       (float*)d_out);
}